// Round 1
// baseline (30283.997 us; speedup 1.0000x reference)
//
#include <hip/hip_runtime.h>
#include <hip/hip_fp16.h>

// GInvariantLSTMLayer: persistent-RNN design for MI355X.
//   X:(64,512,1024) f32, H0:(64,2048) f32, inv_w/inv_b:(4,2048), lin_W:(4,2048,2048), lin_b:(4,2048)
//   out = h_final^T : (2048,64) f32
// One block per CU (256 blocks); each block owns 8 hidden features x 4 gates = 32 weight
// rows resident in LDS (fp16, padded stride). c-state lives in VGPRs for all 512 steps.
// h broadcast via double-buffered global fp16 buffers + custom grid barrier per step.

typedef _Float16 f16x8 __attribute__((ext_vector_type(8)));
typedef float    f32x4 __attribute__((ext_vector_type(4)));

#define LROW 2056   // LDS row stride in halves: 2048 + 8 pad -> 2-way bank aliasing (free)
#define NBLK 256u

__device__ __forceinline__ float fast_sig(float x) {
  return 1.f / (1.f + __expf(-x));
}
__device__ __forceinline__ float fast_tanh(float x) {
  x = fminf(15.f, fmaxf(-15.f, x));
  const float e = __expf(2.f * x);
  return (e - 1.f) / (e + 1.f);
}

// s_all[t*64 + n] = sum_d X[n][t][d].  One wave per (n,t) row.
__global__ void __launch_bounds__(256) seq_sum_kernel(const float* __restrict__ X,
                                                      float* s_all) {
  const int gw   = (int)((blockIdx.x * blockDim.x + threadIdx.x) >> 6); // 0..32767
  const int lane = threadIdx.x & 63;
  const int n = gw >> 9, t = gw & 511;
  const float4* p = (const float4*)(X + ((size_t)gw << 10));
  float s = 0.f;
#pragma unroll
  for (int i = 0; i < 4; ++i) {
    const float4 v = p[lane + (i << 6)];
    s += (v.x + v.y) + (v.z + v.w);
  }
#pragma unroll
  for (int off = 32; off; off >>= 1) s += __shfl_xor(s, off);
  if (lane == 0) s_all[(t << 6) + n] = s;
}

__global__ void bar_init_kernel(unsigned* bar) {
  if (threadIdx.x == 0) *bar = 0u;
}

// Grid barrier: arrival count is monotonic; round r waits for count >= 256*r.
// threadfence = agent-scope acq_rel fence -> L2 writeback + invalidate (cross-XCD visibility).
__device__ __forceinline__ void grid_barrier(unsigned* bar, unsigned round, int tid) {
  __threadfence();          // release: drain + write back this CU's h stores
  __syncthreads();
  if (tid == 0) {
    __hip_atomic_fetch_add(bar, 1u, __ATOMIC_RELAXED, __HIP_MEMORY_SCOPE_AGENT);
    const unsigned target = NBLK * round;
    unsigned guard = 0;
    while (__hip_atomic_load(bar, __ATOMIC_RELAXED, __HIP_MEMORY_SCOPE_AGENT) < target) {
      __builtin_amdgcn_s_sleep(2);
      if (++guard > (1u << 22)) break;  // anti-hang guard; never fires when resident
    }
  }
  __syncthreads();
  __threadfence();          // acquire: invalidate stale L1/L2 h lines
}

__global__ void __launch_bounds__(256) ginv_lstm_persist(
    const float* __restrict__ lin_W, const float* __restrict__ inv_w,
    const float* __restrict__ inv_b, const float* __restrict__ lin_b,
    const float* s_all,               // may alias d_out (fallback) -> no restrict
    const float* __restrict__ H0,
    _Float16* hb0, _Float16* hb1, unsigned* bar, float* out) {
  // 32 rows: r = g*8+k ; tile0 rows 0..15 = gates i,f ; tile1 rows 16..31 = gates g,o
  __shared__ _Float16 Wl[32 * LROW];  // 131584 B (gfx950 has 160 KiB LDS/CU)
  const int blk = blockIdx.x;
  const int tid = threadIdx.x;

  // ---- stage weight slice fp32 -> fp16 LDS (once) ----
  for (int base = tid * 4; base < 32 * 2048; base += 1024) {
    const int r  = base >> 11;
    const int hc = base & 2047;
    const int g  = r >> 3;
    const int kf = r & 7;
    const float4 v =
        *(const float4*)&lin_W[(((size_t)(g * 2048 + blk * 8 + kf)) << 11) + hc];
    _Float16* d = &Wl[r * LROW + hc];
    d[0] = (_Float16)v.x; d[1] = (_Float16)v.y;
    d[2] = (_Float16)v.z; d[3] = (_Float16)v.w;
  }

  // ---- init h(0) from H0 (zeros per setup, honored anyway) ----
  {
    const int i0 = blk * 512 + tid;
    hb0[i0]       = (_Float16)H0[i0];
    hb0[i0 + 256] = (_Float16)H0[i0 + 256];
  }

  const int wave = tid >> 6;
  const int lane = tid & 63;
  const int q    = lane >> 4;   // quad
  const int cc   = lane & 15;   // column within tile = weight-row within tile
  const int kf   = cc & 7;
  const int Kg   = blk * 8 + kf;              // global hidden feature
  const int g0   = (cc < 8) ? 0 : 1;          // tile0 gate for this lane
  const int g1   = (cc < 8) ? 2 : 3;          // tile1 gate
  const float w0 = inv_w[(g0 << 11) + Kg];
  const float b0 = inv_b[(g0 << 11) + Kg] + lin_b[(g0 << 11) + Kg];
  const float w1 = inv_w[(g1 << 11) + Kg];
  const float b1 = inv_b[(g1 << 11) + Kg] + lin_b[(g1 << 11) + Kg];

  unsigned round = 1;
  grid_barrier(bar, round, tid);  // h(0) + all weight staging visible grid-wide

  float cst[4] = {0.f, 0.f, 0.f, 0.f};  // c-state (meaningful in lanes cc<8)

  // A-fragment: lane holds h[m = wave*16+cc][k = q*8 .. q*8+7] per 32-wide K chunk
  const size_t a_off = (((size_t)(wave * 16 + cc)) << 11) + (size_t)(q << 3);
  const int lb0 = cc * LROW + q * 8;
  const int lb1 = (16 + cc) * LROW + q * 8;

  for (int t = 0; t < 512; ++t) {
    const _Float16* hp   = (t & 1) ? hb1 : hb0;
    _Float16*       hcur = (t & 1) ? hb0 : hb1;

    f32x4 acc0 = {0.f, 0.f, 0.f, 0.f};
    f32x4 acc1 = {0.f, 0.f, 0.f, 0.f};
    const f16x8* ap = (const f16x8*)(hp + a_off);
#pragma unroll 8
    for (int kc = 0; kc < 64; ++kc) {
      const f16x8 a   = ap[kc * 4];                              // global, 16 B/lane
      const f16x8 bb0 = *(const f16x8*)&Wl[lb0 + kc * 32];       // ds_read_b128
      const f16x8 bb1 = *(const f16x8*)&Wl[lb1 + kc * 32];
      acc0 = __builtin_amdgcn_mfma_f32_16x16x32_f16(a, bb0, acc0, 0, 0, 0);
      acc1 = __builtin_amdgcn_mfma_f32_16x16x32_f16(a, bb1, acc1, 0, 0, 0);
    }

    // ---- gates.  acc row = batch (quad*4+v), col = cc. ----
    const float4 s4 = *(const float4*)&s_all[(t << 6) + wave * 16 + q * 4];
    const float sv[4] = {s4.x, s4.y, s4.z, s4.w};
    float hnew[4];
#pragma unroll
    for (int v = 0; v < 4; ++v) {
      const float z0 = acc0[v] + sv[v] * w0 + b0;   // lane cc<8: gate i ; cc>=8: gate f
      const float z1 = acc1[v] + sv[v] * w1 + b1;   // lane cc<8: gate g ; cc>=8: gate o
      const float zf = __shfl_xor(z0, 8);           // partner's f (for cc<8)
      const float zo = __shfl_xor(z1, 8);           // partner's o
      const float ig = fast_sig(z0);
      const float fg = fast_sig(zf);
      const float gg = fast_tanh(z1);
      const float og = fast_sig(zo);
      const float cn = fg * cst[v] + ig * gg;
      cst[v] = cn;
      hnew[v] = og * fast_tanh(cn);
    }

    if (t < 511) {
      if (cc < 8) {  // lanes cc<8 own feature Kg; write h slice (fp16)
        _Float16* hw = hcur + (((size_t)(wave * 16 + q * 4)) << 11) + Kg;
        hw[0]          = (_Float16)hnew[0];
        hw[1 << 11]    = (_Float16)hnew[1];
        hw[2 << 11]    = (_Float16)hnew[2];
        hw[3 << 11]    = (_Float16)hnew[3];
      }
      ++round;
      grid_barrier(bar, round, tid);
    } else {
      // barrier BEFORE final write: s_all may live inside d_out (fallback path)
      ++round;
      grid_barrier(bar, round, tid);
      if (cc < 8) {
        const float4 o4 = {hnew[0], hnew[1], hnew[2], hnew[3]};
        *(float4*)&out[(Kg << 6) + wave * 16 + q * 4] = o4;  // out[k][n]
      }
    }
  }
}

extern "C" void kernel_launch(void* const* d_in, const int* in_sizes, int n_in,
                              void* d_out, int out_size, void* d_ws, size_t ws_size,
                              hipStream_t stream) {
  const float* X     = (const float*)d_in[0];
  const float* H0    = (const float*)d_in[1];
  const float* inv_w = (const float*)d_in[2];
  const float* inv_b = (const float*)d_in[3];
  const float* lin_W = (const float*)d_in[4];
  const float* lin_b = (const float*)d_in[5];
  float* out = (float*)d_out;

  const size_t S_BYTES = 512 * 64 * 4;      // 131072
  const size_t BAR_PAD = 4096;
  const size_t H_BYTES = 64 * 2048 * 2;     // 262144 per buffer
  const size_t NEED = S_BYTES + BAR_PAD + 2 * H_BYTES;

  float*    s_all;
  unsigned* bar;
  _Float16* hb0;
  _Float16* hb1;
  if (ws_size >= NEED) {
    char* ws = (char*)d_ws;
    s_all = (float*)ws;
    bar   = (unsigned*)(ws + S_BYTES);
    hb0   = (_Float16*)(ws + S_BYTES + BAR_PAD);
    hb1   = (_Float16*)(ws + S_BYTES + BAR_PAD + H_BYTES);
  } else {
    // Fallback: s_all in d_out (final out written after a grid barrier), h/bar in X's
    // tail (X is fully consumed by seq_sum_kernel, which completes first on-stream).
    s_all = (float*)d_out;
    char* xt = (char*)d_in[0] + (size_t)64 * 512 * 1024 * 4 - (BAR_PAD + 2 * H_BYTES);
    bar = (unsigned*)xt;
    hb0 = (_Float16*)(xt + BAR_PAD);
    hb1 = (_Float16*)(xt + BAR_PAD + H_BYTES);
  }

  seq_sum_kernel<<<8192, 256, 0, stream>>>(X, s_all);
  bar_init_kernel<<<1, 64, 0, stream>>>(bar);
  ginv_lstm_persist<<<256, 256, 0, stream>>>(lin_W, inv_w, inv_b, lin_b, s_all, H0,
                                             hb0, hb1, bar, out);
}

// Round 2
// 11119.615 us; speedup vs baseline: 2.7235x; 2.7235x over previous
//
#include <hip/hip_runtime.h>
#include <hip/hip_fp16.h>

// GInvariantLSTMLayer persistent-RNN, round 2.
// Round-1 lesson: __threadfence() (agent acq_rel) emits buffer_wbl2 sc1 -> full L2
// writeback-invalidate, 2x/step/CU = 59 us/step. Fix: write-through (sc1) h stores +
// acquire-only fence (buffer_inv, no writeback) + two-level barrier.

typedef _Float16 f16x8 __attribute__((ext_vector_type(8)));
typedef float    f32x4 __attribute__((ext_vector_type(4)));

#define LROW 2056   // LDS row stride in halves: 2048 + 8 pad (2-way bank aliasing = free)
#define NBLK 256u

__device__ __forceinline__ float fast_sig(float x) {
  return 1.f / (1.f + __expf(-x));
}
__device__ __forceinline__ float fast_tanh(float x) {
  x = fminf(15.f, fmaxf(-15.f, x));
  const float e = __expf(2.f * x);
  return (e - 1.f) / (e + 1.f);
}

// Write-through fp16 store: relaxed agent-scope atomic -> global_store_short sc0 sc1.
// Lands at the L3 coherence point; no dirty L2 line, so no release-side wbl2 needed.
__device__ __forceinline__ void st_h(_Float16* p, float v) {
  const unsigned short b = __builtin_bit_cast(unsigned short, (_Float16)v);
  __hip_atomic_store((unsigned short*)p, b, __ATOMIC_RELAXED, __HIP_MEMORY_SCOPE_AGENT);
}

// s_all[t*64 + n] = sum_d X[n][t][d].  One wave per (n,t) row.
__global__ void __launch_bounds__(256) seq_sum_kernel(const float* __restrict__ X,
                                                      float* s_all) {
  const int gw   = (int)((blockIdx.x * blockDim.x + threadIdx.x) >> 6);
  const int lane = threadIdx.x & 63;
  const int n = gw >> 9, t = gw & 511;
  const float4* p = (const float4*)(X + ((size_t)gw << 10));
  float s = 0.f;
#pragma unroll
  for (int i = 0; i < 4; ++i) {
    const float4 v = p[lane + (i << 6)];
    s += (v.x + v.y) + (v.z + v.w);
  }
#pragma unroll
  for (int off = 32; off; off >>= 1) s += __shfl_xor(s, off);
  if (lane == 0) s_all[(t << 6) + n] = s;
}

// bar[0..255]: 8 group counters spaced 128 B (index g*32). bar[512]: root counter.
__global__ void bar_init_kernel(unsigned* bar) {
  bar[threadIdx.x]       = 0u;
  bar[threadIdx.x + 256] = 0u;
  bar[threadIdx.x + 512] = 0u;
  bar[threadIdx.x + 768] = 0u;
}

// Two-level monotonic grid barrier. All ops relaxed agent-scope (sc1, L3-homed):
// no wbl2 anywhere. Acquire (buffer_inv) is done by the CALLER per-wave after return.
__device__ __forceinline__ void grid_barrier2(unsigned* bar, unsigned round,
                                              int tid, int blk) {
  asm volatile("s_waitcnt vmcnt(0)" ::: "memory");  // sc1 stores reached coherence pt
  __syncthreads();
  if (tid == 0) {
    unsigned* grp  = bar + ((blk & 7) << 5);  // 32 blocks per group
    unsigned* root = bar + 512;
    const unsigned old =
        __hip_atomic_fetch_add(grp, 1u, __ATOMIC_RELAXED, __HIP_MEMORY_SCOPE_AGENT);
    if (old == 32u * round - 1u)  // last arriver of the group this round
      __hip_atomic_fetch_add(root, 1u, __ATOMIC_RELAXED, __HIP_MEMORY_SCOPE_AGENT);
    const unsigned target = 8u * round;
    unsigned guard = 0;
    while (__hip_atomic_load(root, __ATOMIC_RELAXED, __HIP_MEMORY_SCOPE_AGENT) <
           target) {
      __builtin_amdgcn_s_sleep(1);
      if (++guard > (1u << 23)) break;  // anti-hang guard; never fires when resident
    }
  }
  __syncthreads();
  // Acquire: each wave invalidates stale L1/L2 h lines (buffer_inv, no writeback).
  // Per-wave so each wave's subsequent loads are HW-ordered after its own inv.
  __builtin_amdgcn_fence(__ATOMIC_ACQUIRE, "agent");
}

__global__ void __launch_bounds__(256) ginv_lstm_persist(
    const float* __restrict__ lin_W, const float* __restrict__ inv_w,
    const float* __restrict__ inv_b, const float* __restrict__ lin_b,
    const float* s_all,               // may alias d_out (fallback) -> no restrict
    const float* __restrict__ H0,
    _Float16* hb0, _Float16* hb1, unsigned* bar, float* out) {
  // 32 weight rows: r = g*8+k ; tile0 rows 0..15 = gates i,f ; tile1 = gates g,o
  __shared__ _Float16 Wl[32 * LROW];  // 131584 B of 160 KiB
  const int blk = blockIdx.x;
  const int tid = threadIdx.x;

  // ---- stage weight slice fp32 -> fp16 LDS (once) ----
  for (int base = tid * 4; base < 32 * 2048; base += 1024) {
    const int r  = base >> 11;
    const int hc = base & 2047;
    const int g  = r >> 3;
    const int kf = r & 7;
    const float4 v =
        *(const float4*)&lin_W[(((size_t)(g * 2048 + blk * 8 + kf)) << 11) + hc];
    _Float16* d = &Wl[r * LROW + hc];
    d[0] = (_Float16)v.x; d[1] = (_Float16)v.y;
    d[2] = (_Float16)v.z; d[3] = (_Float16)v.w;
  }

  // ---- init h(0) from H0 (write-through so all XCDs see it) ----
  {
    const int i0 = blk * 512 + tid;
    st_h(&hb0[i0], H0[i0]);
    st_h(&hb0[i0 + 256], H0[i0 + 256]);
  }

  const int wave = tid >> 6;
  const int lane = tid & 63;
  const int q    = lane >> 4;   // quad
  const int cc   = lane & 15;   // column within tile = weight-row within tile
  const int kf   = cc & 7;
  const int Kg   = blk * 8 + kf;              // global hidden feature
  const int g0   = (cc < 8) ? 0 : 1;          // tile0 gate for this lane
  const int g1   = (cc < 8) ? 2 : 3;          // tile1 gate
  const float w0 = inv_w[(g0 << 11) + Kg];
  const float b0 = inv_b[(g0 << 11) + Kg] + lin_b[(g0 << 11) + Kg];
  const float w1 = inv_w[(g1 << 11) + Kg];
  const float b1 = inv_b[(g1 << 11) + Kg] + lin_b[(g1 << 11) + Kg];

  unsigned round = 1;
  grid_barrier2(bar, round, tid, blk);  // h(0) + weights staged grid-wide

  float cst[4] = {0.f, 0.f, 0.f, 0.f};  // c-state (meaningful in lanes cc<8)

  // A-fragment: lane holds h[m = wave*16+cc][k = q*8 .. q*8+7] per 32-wide K chunk
  const size_t a_off = (((size_t)(wave * 16 + cc)) << 11) + (size_t)(q << 3);
  const int lb0 = cc * LROW + q * 8;
  const int lb1 = (16 + cc) * LROW + q * 8;

  for (int t = 0; t < 512; ++t) {
    const _Float16* hp   = (t & 1) ? hb1 : hb0;
    _Float16*       hcur = (t & 1) ? hb0 : hb1;

    f32x4 acc0 = {0.f, 0.f, 0.f, 0.f};
    f32x4 acc1 = {0.f, 0.f, 0.f, 0.f};
    const f16x8* ap = (const f16x8*)(hp + a_off);
#pragma unroll 8
    for (int kc = 0; kc < 64; ++kc) {
      const f16x8 a   = ap[kc * 4];                              // cached, L2-served
      const f16x8 bb0 = *(const f16x8*)&Wl[lb0 + kc * 32];       // ds_read_b128
      const f16x8 bb1 = *(const f16x8*)&Wl[lb1 + kc * 32];
      acc0 = __builtin_amdgcn_mfma_f32_16x16x32_f16(a, bb0, acc0, 0, 0, 0);
      acc1 = __builtin_amdgcn_mfma_f32_16x16x32_f16(a, bb1, acc1, 0, 0, 0);
    }

    // ---- gates.  acc row = batch (q*4+v), col = cc. ----
    const float4 s4 = *(const float4*)&s_all[(t << 6) + wave * 16 + q * 4];
    const float sv[4] = {s4.x, s4.y, s4.z, s4.w};
    float hnew[4];
#pragma unroll
    for (int v = 0; v < 4; ++v) {
      const float z0 = acc0[v] + sv[v] * w0 + b0;   // cc<8: gate i ; cc>=8: gate f
      const float z1 = acc1[v] + sv[v] * w1 + b1;   // cc<8: gate g ; cc>=8: gate o
      const float zf = __shfl_xor(z0, 8);
      const float zo = __shfl_xor(z1, 8);
      const float ig = fast_sig(z0);
      const float fg = fast_sig(zf);
      const float gg = fast_tanh(z1);
      const float og = fast_sig(zo);
      const float cn = fg * cst[v] + ig * gg;
      cst[v] = cn;
      hnew[v] = og * fast_tanh(cn);
    }

    if (t < 511) {
      if (cc < 8) {  // lanes cc<8 own feature Kg; write-through h slice
        _Float16* hw = hcur + (((size_t)(wave * 16 + q * 4)) << 11) + Kg;
        st_h(hw + (0 << 11), hnew[0]);
        st_h(hw + (1 << 11), hnew[1]);
        st_h(hw + (2 << 11), hnew[2]);
        st_h(hw + (3 << 11), hnew[3]);
      }
      ++round;
      grid_barrier2(bar, round, tid, blk);
    } else {
      // barrier BEFORE final write: s_all may live inside d_out (fallback path)
      ++round;
      grid_barrier2(bar, round, tid, blk);
      if (cc < 8) {
        const float4 o4 = {hnew[0], hnew[1], hnew[2], hnew[3]};
        *(float4*)&out[(Kg << 6) + wave * 16 + q * 4] = o4;  // out[k][n]
      }
    }
  }
}

extern "C" void kernel_launch(void* const* d_in, const int* in_sizes, int n_in,
                              void* d_out, int out_size, void* d_ws, size_t ws_size,
                              hipStream_t stream) {
  const float* X     = (const float*)d_in[0];
  const float* H0    = (const float*)d_in[1];
  const float* inv_w = (const float*)d_in[2];
  const float* inv_b = (const float*)d_in[3];
  const float* lin_W = (const float*)d_in[4];
  const float* lin_b = (const float*)d_in[5];
  float* out = (float*)d_out;

  const size_t S_BYTES = 512 * 64 * 4;      // 131072
  const size_t BAR_PAD = 4096;
  const size_t H_BYTES = 64 * 2048 * 2;     // 262144 per buffer
  const size_t NEED = S_BYTES + BAR_PAD + 2 * H_BYTES;

  float*    s_all;
  unsigned* bar;
  _Float16* hb0;
  _Float16* hb1;
  if (ws_size >= NEED) {
    char* ws = (char*)d_ws;
    s_all = (float*)ws;
    bar   = (unsigned*)(ws + S_BYTES);
    hb0   = (_Float16*)(ws + S_BYTES + BAR_PAD);
    hb1   = (_Float16*)(ws + S_BYTES + BAR_PAD + H_BYTES);
  } else {
    // Fallback: s_all in d_out (final out written after a grid barrier), h/bar in X's
    // tail (X fully consumed by seq_sum_kernel, which completes first on-stream).
    s_all = (float*)d_out;
    char* xt = (char*)d_in[0] + (size_t)64 * 512 * 1024 * 4 - (BAR_PAD + 2 * H_BYTES);
    bar = (unsigned*)xt;
    hb0 = (_Float16*)(xt + BAR_PAD);
    hb1 = (_Float16*)(xt + BAR_PAD + H_BYTES);
  }

  seq_sum_kernel<<<8192, 256, 0, stream>>>(X, s_all);
  bar_init_kernel<<<1, 256, 0, stream>>>(bar);
  ginv_lstm_persist<<<256, 256, 0, stream>>>(lin_W, inv_w, inv_b, lin_b, s_all, H0,
                                             hb0, hb1, bar, out);
}

// Round 3
// 6546.192 us; speedup vs baseline: 4.6262x; 1.6986x over previous
//
#include <hip/hip_runtime.h>
#include <hip/hip_fp16.h>

// GInvariantLSTMLayer persistent-RNN, round 3.
// Round-2 lesson: per-wave acquire fence (buffer_inv sc1) = 1024 full-L2 invalidates
// per step -> ~21 us/step serializer, and it defeats L2 caching of h anyway.
// Round-3: ZERO cache-maintenance ops in the loop. h loads are relaxed agent-scope
// atomics (global_load_dwordx2 sc1 -> read straight from the L3 coherence point);
// h buffer re-laid-out in exact MFMA-fragment order so every 8-B load instruction is
// 64x8B fully contiguous (512 B, no over-fetch). Stores stay write-through sc1.

typedef _Float16 f16x8 __attribute__((ext_vector_type(8)));
typedef float    f32x4 __attribute__((ext_vector_type(4)));
typedef unsigned long long u64;

#define LROW 2056   // LDS row stride in halves: 2048 + 8 pad
#define NBLK 256u

static __device__ __forceinline__ float fast_sig(float x) {
  return 1.f / (1.f + __expf(-x));
}
static __device__ __forceinline__ float fast_tanh(float x) {
  x = fminf(15.f, fmaxf(-15.f, x));
  const float e = __expf(2.f * x);
  return (e - 1.f) / (e + 1.f);
}

// Write-through fp16 store: relaxed agent atomic -> global_store_short sc0 sc1.
static __device__ __forceinline__ void st_h16(void* p, float v) {
  const unsigned short b = __builtin_bit_cast(unsigned short, (_Float16)v);
  __hip_atomic_store((unsigned short*)p, b, __ATOMIC_RELAXED, __HIP_MEMORY_SCOPE_AGENT);
}
// Coherent 8-B load: relaxed agent atomic -> global_load_dwordx2 sc1 (L2 bypass).
static __device__ __forceinline__ u64 ld_h64(const void* p) {
  return __hip_atomic_load((const u64*)p, __ATOMIC_RELAXED, __HIP_MEMORY_SCOPE_AGENT);
}

// Packed h layout: element (n, j) at byte offset
//   (n>>4)<<16 | kc<<10 | half<<9 | ((m*4+q)<<3) | ii<<1
// with m=n&15, kc=j>>5, kj=j&31, q=kj>>3, i=kj&7, half=i>>2, ii=i&3.
// => one dwordx2 fragment-load instruction (64 lanes) reads 512 contiguous bytes.
static __device__ __forceinline__ int h_off(int n, int j) {
  const int w = n >> 4, m = n & 15, kc = j >> 5, kj = j & 31;
  const int q = kj >> 3, i = kj & 7;
  return (w << 16) + (kc << 10) + ((i >> 2) << 9) + (((m << 2) + q) << 3) +
         ((i & 3) << 1);
}

// s_all[t*64 + n] = sum_d X[n][t][d].  One wave per (n,t) row.
__global__ void __launch_bounds__(256) seq_sum_kernel(const float* __restrict__ X,
                                                      float* s_all) {
  const int gw   = (int)((blockIdx.x * blockDim.x + threadIdx.x) >> 6);
  const int lane = threadIdx.x & 63;
  const int n = gw >> 9, t = gw & 511;
  const float4* p = (const float4*)(X + ((size_t)gw << 10));
  float s = 0.f;
#pragma unroll
  for (int i = 0; i < 4; ++i) {
    const float4 v = p[lane + (i << 6)];
    s += (v.x + v.y) + (v.z + v.w);
  }
#pragma unroll
  for (int off = 32; off; off >>= 1) s += __shfl_xor(s, off);
  if (lane == 0) s_all[(t << 6) + n] = s;
}

// bar[0..255]: 8 group counters spaced 128 B (index g*32). bar[512]: root counter.
__global__ void bar_init_kernel(unsigned* bar) {
  bar[threadIdx.x]       = 0u;
  bar[threadIdx.x + 256] = 0u;
  bar[threadIdx.x + 512] = 0u;
  bar[threadIdx.x + 768] = 0u;
}

// Two-level monotonic grid barrier; all ops relaxed agent-scope (L3-homed).
// NO fences / invalidates: h communication is handled by sc1 loads/stores.
static __device__ __forceinline__ void grid_barrier2(unsigned* bar, unsigned round,
                                                     int tid, int blk) {
  asm volatile("s_waitcnt vmcnt(0)" ::: "memory");  // sc1 h-stores at coherence pt
  __syncthreads();
  if (tid == 0) {
    unsigned* grp  = bar + ((blk & 7) << 5);  // 32 blocks per group
    unsigned* root = bar + 512;
    const unsigned old =
        __hip_atomic_fetch_add(grp, 1u, __ATOMIC_RELAXED, __HIP_MEMORY_SCOPE_AGENT);
    if (old == 32u * round - 1u)
      __hip_atomic_fetch_add(root, 1u, __ATOMIC_RELAXED, __HIP_MEMORY_SCOPE_AGENT);
    const unsigned target = 8u * round;
    unsigned guard = 0;
    while (__hip_atomic_load(root, __ATOMIC_RELAXED, __HIP_MEMORY_SCOPE_AGENT) <
           target) {
      __builtin_amdgcn_s_sleep(1);
      if (++guard > (1u << 23)) break;  // anti-hang guard; never fires when resident
    }
  }
  __syncthreads();
}

__global__ void __launch_bounds__(256) ginv_lstm_persist(
    const float* __restrict__ lin_W, const float* __restrict__ inv_w,
    const float* __restrict__ inv_b, const float* __restrict__ lin_b,
    const float* s_all,               // may alias d_out (fallback) -> no restrict
    const float* __restrict__ H0,
    _Float16* hb0, _Float16* hb1, unsigned* bar, float* out) {
  // 32 weight rows: r = g*8+k ; tile0 rows 0..15 = gates i,f ; tile1 = gates g,o
  __shared__ _Float16 Wl[32 * LROW];  // 131584 B of 160 KiB
  const int blk = blockIdx.x;
  const int tid = threadIdx.x;

  // ---- stage weight slice fp32 -> fp16 LDS (once) ----
  for (int base = tid * 4; base < 32 * 2048; base += 1024) {
    const int r  = base >> 11;
    const int hc = base & 2047;
    const int g  = r >> 3;
    const int kf = r & 7;
    const float4 v =
        *(const float4*)&lin_W[(((size_t)(g * 2048 + blk * 8 + kf)) << 11) + hc];
    _Float16* d = &Wl[r * LROW + hc];
    d[0] = (_Float16)v.x; d[1] = (_Float16)v.y;
    d[2] = (_Float16)v.z; d[3] = (_Float16)v.w;
  }

  // ---- init h(0) from H0 into packed layout (write-through) ----
  {
    int i0 = blk * 512 + tid;
    st_h16((char*)hb0 + h_off(i0 >> 11, i0 & 2047), H0[i0]);
    i0 += 256;
    st_h16((char*)hb0 + h_off(i0 >> 11, i0 & 2047), H0[i0]);
  }

  const int wave = tid >> 6;
  const int lane = tid & 63;
  const int q    = lane >> 4;   // quad
  const int cc   = lane & 15;   // column within tile = weight-row within tile
  const int kf   = cc & 7;
  const int Kg   = blk * 8 + kf;              // global hidden feature
  const int g0   = (cc < 8) ? 0 : 1;          // tile0 gate for this lane
  const int g1   = (cc < 8) ? 2 : 3;          // tile1 gate
  const float w0 = inv_w[(g0 << 11) + Kg];
  const float b0 = inv_b[(g0 << 11) + Kg] + lin_b[(g0 << 11) + Kg];
  const float w1 = inv_w[(g1 << 11) + Kg];
  const float b1 = inv_b[(g1 << 11) + Kg] + lin_b[(g1 << 11) + Kg];

  unsigned round = 1;
  grid_barrier2(bar, round, tid, blk);  // h(0) + weights staged grid-wide

  float cst[4] = {0.f, 0.f, 0.f, 0.f};  // c-state (meaningful in lanes cc<8)

  // Consumer: wave reads rows 16*wave..16*wave+15; lane(cc,q) fragment at
  // packed offset (wave<<16) + (kc<<10) + {0,512} + (cc*4+q)*8.
  const int lane_lo = (((cc << 2) + q) << 3);

  // Producer store base: feature Kg -> fixed (kc_t, q_t, i_t); rows m=q*4+v.
  const int kc_t = Kg >> 5;
  const int kj_t = Kg & 31;
  const int q_t  = kj_t >> 3;
  const int i_t  = kj_t & 7;
  const int st_base = (wave << 16) + (kc_t << 10) + ((i_t >> 2) << 9) +
                      (((q << 4) + q_t) << 3) + ((i_t & 3) << 1);

  for (int t = 0; t < 512; ++t) {
    const _Float16* hp   = (t & 1) ? hb1 : hb0;
    _Float16*       hcur = (t & 1) ? hb0 : hb1;

    f32x4 acc0 = {0.f, 0.f, 0.f, 0.f};
    f32x4 acc1 = {0.f, 0.f, 0.f, 0.f};
    const char* hpb = (const char*)hp + (wave << 16) + lane_lo;
    const int lb0 = cc * LROW + q * 8;
    const int lb1 = (16 + cc) * LROW + q * 8;
#pragma unroll 8
    for (int kc = 0; kc < 64; ++kc) {
      union { u64 w[2]; f16x8 v; } ua;
      ua.w[0] = ld_h64(hpb + (kc << 10));        // sc1, 512 B coalesced/instr
      ua.w[1] = ld_h64(hpb + (kc << 10) + 512);
      const f16x8 bb0 = *(const f16x8*)&Wl[lb0 + kc * 32];   // ds_read_b128
      const f16x8 bb1 = *(const f16x8*)&Wl[lb1 + kc * 32];
      acc0 = __builtin_amdgcn_mfma_f32_16x16x32_f16(ua.v, bb0, acc0, 0, 0, 0);
      acc1 = __builtin_amdgcn_mfma_f32_16x16x32_f16(ua.v, bb1, acc1, 0, 0, 0);
    }

    // ---- gates.  acc row = batch (q*4+v), col = cc. ----
    const float4 s4 = *(const float4*)&s_all[(t << 6) + wave * 16 + q * 4];
    const float sv[4] = {s4.x, s4.y, s4.z, s4.w};
    float hnew[4];
#pragma unroll
    for (int v = 0; v < 4; ++v) {
      const float z0 = acc0[v] + sv[v] * w0 + b0;   // cc<8: gate i ; cc>=8: gate f
      const float z1 = acc1[v] + sv[v] * w1 + b1;   // cc<8: gate g ; cc>=8: gate o
      const float zf = __shfl_xor(z0, 8);
      const float zo = __shfl_xor(z1, 8);
      const float ig = fast_sig(z0);
      const float fg = fast_sig(zf);
      const float gg = fast_tanh(z1);
      const float og = fast_sig(zo);
      const float cn = fg * cst[v] + ig * gg;
      cst[v] = cn;
      hnew[v] = og * fast_tanh(cn);
    }

    if (t < 511) {
      if (cc < 8) {  // lanes cc<8 own feature Kg; write-through packed h slice
        char* hw = (char*)hcur + st_base;
        st_h16(hw +  0, hnew[0]);
        st_h16(hw + 32, hnew[1]);
        st_h16(hw + 64, hnew[2]);
        st_h16(hw + 96, hnew[3]);
      }
      ++round;
      grid_barrier2(bar, round, tid, blk);
    } else {
      // barrier BEFORE final write: s_all may live inside d_out (fallback path)
      ++round;
      grid_barrier2(bar, round, tid, blk);
      if (cc < 8) {
        const float4 o4 = {hnew[0], hnew[1], hnew[2], hnew[3]};
        *(float4*)&out[(Kg << 6) + wave * 16 + q * 4] = o4;  // out[k][n]
      }
    }
  }
}

extern "C" void kernel_launch(void* const* d_in, const int* in_sizes, int n_in,
                              void* d_out, int out_size, void* d_ws, size_t ws_size,
                              hipStream_t stream) {
  const float* X     = (const float*)d_in[0];
  const float* H0    = (const float*)d_in[1];
  const float* inv_w = (const float*)d_in[2];
  const float* inv_b = (const float*)d_in[3];
  const float* lin_W = (const float*)d_in[4];
  const float* lin_b = (const float*)d_in[5];
  float* out = (float*)d_out;

  const size_t S_BYTES = 512 * 64 * 4;      // 131072
  const size_t BAR_PAD = 4096;
  const size_t H_BYTES = 64 * 2048 * 2;     // 262144 per buffer (packed layout)
  const size_t NEED = S_BYTES + BAR_PAD + 2 * H_BYTES;

  float*    s_all;
  unsigned* bar;
  _Float16* hb0;
  _Float16* hb1;
  if (ws_size >= NEED) {
    char* ws = (char*)d_ws;
    s_all = (float*)ws;
    bar   = (unsigned*)(ws + S_BYTES);
    hb0   = (_Float16*)(ws + S_BYTES + BAR_PAD);
    hb1   = (_Float16*)(ws + S_BYTES + BAR_PAD + H_BYTES);
  } else {
    // Fallback: s_all in d_out (final out written after a grid barrier), h/bar in X's
    // tail (X fully consumed by seq_sum_kernel, which completes first on-stream).
    s_all = (float*)d_out;
    char* xt = (char*)d_in[0] + (size_t)64 * 512 * 1024 * 4 - (BAR_PAD + 2 * H_BYTES);
    bar = (unsigned*)xt;
    hb0 = (_Float16*)(xt + BAR_PAD);
    hb1 = (_Float16*)(xt + BAR_PAD + H_BYTES);
  }

  seq_sum_kernel<<<8192, 256, 0, stream>>>(X, s_all);
  bar_init_kernel<<<1, 256, 0, stream>>>(bar);
  ginv_lstm_persist<<<256, 256, 0, stream>>>(lin_W, inv_w, inv_b, lin_b, s_all, H0,
                                             hb0, hb1, bar, out);
}